// Round 1
// baseline (720.767 us; speedup 1.0000x reference)
//
#include <hip/hip_runtime.h>

// Problem: B=16, L1=L2=1024, H=768
//   P = relu(X @ W^T + b) for X in {x1,x2}  (shared Linear)
//   S[b,i,j] = <P1[b,i], P2[b,j]>, mask x2_mask -> -inf, softmax over j
//   att = alpha @ x2 ; out = concat([x1, att, x1*att, x1-att], -1)
//
// Precision: hi/lo split-bf16 3-pass MFMA for projection + scores GEMMs
// (logits ~200; single bf16 would perturb softmax ties past threshold).
// att GEMM + concat are error-benign -> single-pass bf16 / fp32.
//
// Memory plan:
//   d_out[0      .. 50.3MB)  : P_hi  (bf16, 32768x768)   } scratch, overwritten
//   d_out[50.3MB ..100.7MB)  : P_lo  (bf16, 32768x768)   } by k_concat at end
//   d_out[100.7MB..167.8MB)  : scores/alpha (fp32 16x1024x1024)
//   d_ws [0      .. 50.3MB)  : att (fp32 16384x768)

#define B_  16
#define L_  1024
#define H_  768
#define M1_ (B_ * L_)    // 16384 rows for x1
#define MT_ (2 * M1_)    // 32768 combined rows

using f32x4  = __attribute__((ext_vector_type(4))) float;
using bf16x8 = __attribute__((ext_vector_type(8))) __bf16;
using u16x8  = __attribute__((ext_vector_type(8))) unsigned short;
using u16x4  = __attribute__((ext_vector_type(4))) unsigned short;

__device__ inline unsigned short f2b(float f) {
  unsigned u = __builtin_bit_cast(unsigned, f);
  u += 0x7FFFu + ((u >> 16) & 1u);   // RNE; data has no NaN/inf
  return (unsigned short)(u >> 16);
}
__device__ inline float b2f(unsigned short u) {
  return __builtin_bit_cast(float, ((unsigned)u) << 16);
}

// LDS tile row stride = 40 ushorts (80 B) : 16B-aligned rows, breaks pow2 bank stride
__device__ inline bf16x8 ld_frag(const unsigned short* lds, int row, int quad) {
  u16x8 v = *(const u16x8*)(lds + row * 40 + quad * 8);
  return __builtin_bit_cast(bf16x8, v);
}

#define MFMA(a, b, c) __builtin_amdgcn_mfma_f32_16x16x32_bf16((a), (b), (c), 0, 0, 0)

// ---------------- K1: P = relu([x1;x2] @ W^T + b), store hi/lo bf16 -------------
__global__ __launch_bounds__(256) void k_proj(
    const float* __restrict__ x1, const float* __restrict__ x2,
    const float* __restrict__ W, const float* __restrict__ bias,
    unsigned short* __restrict__ Ph, unsigned short* __restrict__ Pl)
{
  __shared__ unsigned short Ah[128 * 40];
  __shared__ unsigned short Al[128 * 40];
  __shared__ unsigned short Bh[128 * 40];
  __shared__ unsigned short Bl[128 * 40];

  const int tid  = threadIdx.x;
  const int lane = tid & 63, wv = tid >> 6;
  const int wr = wv >> 1, wc = wv & 1;
  const int quad = lane >> 4, lx = lane & 15;

  const int n0 = blockIdx.x * 128;   // h (output feature) tile
  const int m0 = blockIdx.y * 128;   // row tile (0..255; 128 tiles x1, 128 x2)
  const float* Xb = (m0 < M1_) ? (x1 + (size_t)m0 * H_)
                               : (x2 + (size_t)(m0 - M1_) * H_);

  const int srow = tid >> 1;
  const int scol = (tid & 1) * 16;

  f32x4 acc[4][4] = {};

  for (int k0 = 0; k0 < H_; k0 += 32) {
    __syncthreads();
    const float* sa = Xb + (size_t)srow * H_ + k0 + scol;
    const float* sb = W + (size_t)(n0 + srow) * H_ + k0 + scol;
#pragma unroll
    for (int c = 0; c < 16; c += 4) {
      f32x4 va = *(const f32x4*)(sa + c);
      f32x4 vb = *(const f32x4*)(sb + c);
      u16x4 ha, la, hb, lb;
#pragma unroll
      for (int q = 0; q < 4; ++q) {
        ha[q] = f2b(va[q]); la[q] = f2b(va[q] - b2f(ha[q]));
        hb[q] = f2b(vb[q]); lb[q] = f2b(vb[q] - b2f(hb[q]));
      }
      *(u16x4*)(Ah + srow * 40 + scol + c) = ha;
      *(u16x4*)(Al + srow * 40 + scol + c) = la;
      *(u16x4*)(Bh + srow * 40 + scol + c) = hb;
      *(u16x4*)(Bl + srow * 40 + scol + c) = lb;
    }
    __syncthreads();

    bf16x8 fah[4], fal[4], fbh[4], fbl[4];
#pragma unroll
    for (int t = 0; t < 4; ++t) {
      fah[t] = ld_frag(Ah, wr * 64 + t * 16 + lx, quad);
      fal[t] = ld_frag(Al, wr * 64 + t * 16 + lx, quad);
      fbh[t] = ld_frag(Bh, wc * 64 + t * 16 + lx, quad);
      fbl[t] = ld_frag(Bl, wc * 64 + t * 16 + lx, quad);
    }
#pragma unroll
    for (int i = 0; i < 4; ++i)
#pragma unroll
      for (int j = 0; j < 4; ++j) {
        acc[i][j] = MFMA(fah[i], fbh[j], acc[i][j]);
        acc[i][j] = MFMA(fah[i], fbl[j], acc[i][j]);
        acc[i][j] = MFMA(fal[i], fbh[j], acc[i][j]);
      }
  }

#pragma unroll
  for (int j = 0; j < 4; ++j) {
    const int h = n0 + wc * 64 + j * 16 + lx;
    const float bv = bias[h];
#pragma unroll
    for (int i = 0; i < 4; ++i) {
      const int mb = m0 + wr * 64 + i * 16 + quad * 4;
#pragma unroll
      for (int r = 0; r < 4; ++r) {
        float v = acc[i][j][r] + bv;
        v = v > 0.f ? v : 0.f;
        const unsigned short hh = f2b(v);
        const unsigned short ll = f2b(v - b2f(hh));
        const size_t off = (size_t)(mb + r) * H_ + h;
        Ph[off] = hh;
        Pl[off] = ll;
      }
    }
  }
}

// ---------------- K2: scores[b,i,j] = <P1[b,i], P2[b,j]>, masked ----------------
__global__ __launch_bounds__(256) void k_scores(
    const unsigned short* __restrict__ Ph, const unsigned short* __restrict__ Pl,
    const int* __restrict__ x2_mask, float* __restrict__ scores)
{
  __shared__ unsigned short Ah[128 * 40];
  __shared__ unsigned short Al[128 * 40];
  __shared__ unsigned short Bh[128 * 40];
  __shared__ unsigned short Bl[128 * 40];

  const int tid  = threadIdx.x;
  const int lane = tid & 63, wv = tid >> 6;
  const int wr = wv >> 1, wc = wv & 1;
  const int quad = lane >> 4, lx = lane & 15;

  const int j0 = blockIdx.x * 128;
  const int i0 = blockIdx.y * 128;
  const int b  = blockIdx.z;

  const size_t arow = (size_t)(b * L_ + i0);
  const size_t brow = (size_t)(M1_ + b * L_ + j0);

  const int srow = tid >> 1;
  const int scol = (tid & 1) * 16;

  f32x4 acc[4][4] = {};

  for (int k0 = 0; k0 < H_; k0 += 32) {
    __syncthreads();
    const size_t aoff = (arow + srow) * H_ + k0 + scol;
    const size_t boff = (brow + srow) * H_ + k0 + scol;
#pragma unroll
    for (int c = 0; c < 16; c += 8) {
      *(u16x8*)(Ah + srow * 40 + scol + c) = *(const u16x8*)(Ph + aoff + c);
      *(u16x8*)(Al + srow * 40 + scol + c) = *(const u16x8*)(Pl + aoff + c);
      *(u16x8*)(Bh + srow * 40 + scol + c) = *(const u16x8*)(Ph + boff + c);
      *(u16x8*)(Bl + srow * 40 + scol + c) = *(const u16x8*)(Pl + boff + c);
    }
    __syncthreads();

    bf16x8 fah[4], fal[4], fbh[4], fbl[4];
#pragma unroll
    for (int t = 0; t < 4; ++t) {
      fah[t] = ld_frag(Ah, wr * 64 + t * 16 + lx, quad);
      fal[t] = ld_frag(Al, wr * 64 + t * 16 + lx, quad);
      fbh[t] = ld_frag(Bh, wc * 64 + t * 16 + lx, quad);
      fbl[t] = ld_frag(Bl, wc * 64 + t * 16 + lx, quad);
    }
#pragma unroll
    for (int i = 0; i < 4; ++i)
#pragma unroll
      for (int j = 0; j < 4; ++j) {
        acc[i][j] = MFMA(fah[i], fbh[j], acc[i][j]);
        acc[i][j] = MFMA(fah[i], fbl[j], acc[i][j]);
        acc[i][j] = MFMA(fal[i], fbh[j], acc[i][j]);
      }
  }

#pragma unroll
  for (int j = 0; j < 4; ++j) {
    const int jj = j0 + wc * 64 + j * 16 + lx;
    const int mv = x2_mask[b * L_ + jj];   // nonzero => masked
#pragma unroll
    for (int i = 0; i < 4; ++i) {
      const int ib = i0 + wr * 64 + i * 16 + quad * 4;
#pragma unroll
      for (int r = 0; r < 4; ++r) {
        const float v = mv ? -1e30f : acc[i][j][r];
        scores[((size_t)(b * L_) + ib + r) * L_ + jj] = v;
      }
    }
  }
}

// ---------------- K3: row softmax over j, in place ------------------------------
__global__ __launch_bounds__(256) void k_softmax(float* __restrict__ scores)
{
  const size_t row = blockIdx.x;
  float* p = scores + row * L_;
  const int tid = threadIdx.x;

  f32x4 v = *(const f32x4*)(p + tid * 4);
  float m = fmaxf(fmaxf(v[0], v[1]), fmaxf(v[2], v[3]));
#pragma unroll
  for (int off = 32; off > 0; off >>= 1) m = fmaxf(m, __shfl_down(m, off));

  __shared__ float rmax[4];
  __shared__ float rsum[4];
  const int wid = tid >> 6, lane = tid & 63;
  if (lane == 0) rmax[wid] = m;
  __syncthreads();
  m = fmaxf(fmaxf(rmax[0], rmax[1]), fmaxf(rmax[2], rmax[3]));

  f32x4 e;
#pragma unroll
  for (int q = 0; q < 4; ++q) e[q] = __expf(v[q] - m);
  float s = e[0] + e[1] + e[2] + e[3];
#pragma unroll
  for (int off = 32; off > 0; off >>= 1) s += __shfl_down(s, off);
  if (lane == 0) rsum[wid] = s;
  __syncthreads();
  s = rsum[0] + rsum[1] + rsum[2] + rsum[3];

  const float inv = 1.0f / s;   // >=1 unmasked element guaranteed -> s >= 1
#pragma unroll
  for (int q = 0; q < 4; ++q) e[q] *= inv;
  *(f32x4*)(p + tid * 4) = e;
}

// ---------------- K4: att[b,i,d] = sum_j alpha[b,i,j] * x2[b,j,d] ---------------
__global__ __launch_bounds__(256) void k_att(
    const float* __restrict__ alpha, const float* __restrict__ x2,
    float* __restrict__ att)
{
  __shared__ unsigned short Aa[128 * 40];   // alpha tile [i][j]
  __shared__ unsigned short Bt[128 * 40];   // x2^T tile  [d][j]

  const int tid  = threadIdx.x;
  const int lane = tid & 63, wv = tid >> 6;
  const int wr = wv >> 1, wc = wv & 1;
  const int quad = lane >> 4, lx = lane & 15;

  const int d0 = blockIdx.x * 128;
  const int i0 = blockIdx.y * 128;
  const int b  = blockIdx.z;

  const int srow = tid >> 1;
  const int scol = (tid & 1) * 16;

  f32x4 acc[4][4] = {};

  for (int j0 = 0; j0 < L_; j0 += 32) {
    __syncthreads();
    // A: alpha [128 i][32 j] fp32 -> bf16 (single precision pass is enough)
    const float* sa = alpha + ((size_t)(b * L_) + i0 + srow) * L_ + j0 + scol;
#pragma unroll
    for (int c = 0; c < 16; c += 4) {
      f32x4 va = *(const f32x4*)(sa + c);
      u16x4 h;
#pragma unroll
      for (int q = 0; q < 4; ++q) h[q] = f2b(va[q]);
      *(u16x4*)(Aa + srow * 40 + scol + c) = h;
    }
    // B: x2 [32 j][128 d] -> transposed LDS Bt[d][j]
#pragma unroll
    for (int pp = 0; pp < 4; ++pp) {
      const int idx = tid + pp * 256;
      const int jj  = idx >> 5;
      const int dd  = (idx & 31) * 4;
      f32x4 vb = *(const f32x4*)(x2 + ((size_t)(b * L_) + j0 + jj) * H_ + d0 + dd);
#pragma unroll
      for (int q = 0; q < 4; ++q) Bt[(dd + q) * 40 + jj] = f2b(vb[q]);
    }
    __syncthreads();

    bf16x8 fa[4], fb[4];
#pragma unroll
    for (int t = 0; t < 4; ++t) {
      fa[t] = ld_frag(Aa, wr * 64 + t * 16 + lx, quad);
      fb[t] = ld_frag(Bt, wc * 64 + t * 16 + lx, quad);
    }
#pragma unroll
    for (int i = 0; i < 4; ++i)
#pragma unroll
      for (int j = 0; j < 4; ++j)
        acc[i][j] = MFMA(fa[i], fb[j], acc[i][j]);
  }

#pragma unroll
  for (int j = 0; j < 4; ++j) {
    const int dd = d0 + wc * 64 + j * 16 + lx;
#pragma unroll
    for (int i = 0; i < 4; ++i) {
      const int ib = i0 + wr * 64 + i * 16 + quad * 4;
#pragma unroll
      for (int r = 0; r < 4; ++r)
        att[((size_t)(b * L_) + ib + r) * H_ + dd] = acc[i][j][r];
    }
  }
}

// ---------------- K5: out = [x1, att, x1*att, x1-att] ---------------------------
__global__ __launch_bounds__(256) void k_concat(
    const float* __restrict__ x1, const float* __restrict__ att,
    float* __restrict__ out)
{
  const int gid = blockIdx.x * 256 + threadIdx.x;   // 16384 * 192 threads
  const int row = gid / 192;
  const int c   = (gid % 192) * 4;

  f32x4 xv = *(const f32x4*)(x1  + (size_t)row * H_ + c);
  f32x4 av = *(const f32x4*)(att + (size_t)row * H_ + c);
  f32x4 mv, sv;
#pragma unroll
  for (int q = 0; q < 4; ++q) { mv[q] = xv[q] * av[q]; sv[q] = xv[q] - av[q]; }

  float* ob = out + (size_t)row * (4 * H_) + c;
  *(f32x4*)(ob)            = xv;
  *(f32x4*)(ob + H_)       = av;
  *(f32x4*)(ob + 2 * H_)   = mv;
  *(f32x4*)(ob + 3 * H_)   = sv;
}

extern "C" void kernel_launch(void* const* d_in, const int* in_sizes, int n_in,
                              void* d_out, int out_size, void* d_ws, size_t ws_size,
                              hipStream_t stream) {
  const float* x1      = (const float*)d_in[0];
  const float* x2      = (const float*)d_in[1];
  // d_in[2] = x1_mask : unused by the reference output
  const int*   x2_mask = (const int*)d_in[3];
  const float* W       = (const float*)d_in[4];
  const float* bias    = (const float*)d_in[5];
  float* out = (float*)d_out;

  unsigned short* Ph = (unsigned short*)d_out;                                   // 50,331,648 B
  unsigned short* Pl = (unsigned short*)((char*)d_out + (size_t)MT_ * H_ * 2);   // next 50,331,648 B
  float* scores      = (float*)((char*)d_out + (size_t)MT_ * H_ * 4);            // 67,108,864 B
  float* att         = (float*)d_ws;                                             // 50,331,648 B

  k_proj   <<<dim3(6, 256),   256, 0, stream>>>(x1, x2, W, bias, Ph, Pl);
  k_scores <<<dim3(8, 8, 16), 256, 0, stream>>>(Ph, Pl, x2_mask, scores);
  k_softmax<<<dim3(16384),    256, 0, stream>>>(scores);
  k_att    <<<dim3(6, 8, 16), 256, 0, stream>>>(scores, x2, att);
  k_concat <<<dim3(12288),    256, 0, stream>>>(x1, att, out);
}

// Round 2
// 649.258 us; speedup vs baseline: 1.1101x; 1.1101x over previous
//
#include <hip/hip_runtime.h>

// B=16, L1=L2=1024, H=768
// P = relu([x1;x2] @ W^T + b); S = P1·P2^T masked; softmax; att = alpha·x2;
// out = [x1, att, x1*att, x1-att]
//
// Numerics identical to the passing round-1 version (hi/lo split-bf16 3-pass
// MFMA for proj+scores; single-pass bf16 for att). Staging rewritten to
// global_load_lds width-16 with XOR-swizzled LDS tiles (no VALU cvt in GEMMs).
//
// d_out layout (lifetimes):
//   [0,50.3M)        Ph (proj->scores), then alpha_bf16 [0,33.5M) (softmax->att)
//   [50.3M,100.7M)   Pl
//   [100.7M,167.8M)  Xh (split->proj), then scores fp32 (scores->softmax)
//   [167.8M,169.0M)  Wh   [169.0M,170.1M) Wl   [170.1M,195.3M) x2T bf16
// d_ws: [0,50.3M) Xl (split->proj), then att fp32 (att->concat)

#define B_  16
#define L_  1024
#define H_  768
#define M1_ (B_ * L_)    // 16384
#define MT_ (2 * M1_)    // 32768

#define XB_  24576       // k_split blocks for X hi/lo
#define WB_  576         // k_split blocks for W hi/lo
#define TB_  3072        // k_split blocks for x2 transpose

using f32x4  = __attribute__((ext_vector_type(4))) float;
using bf16x8 = __attribute__((ext_vector_type(8))) __bf16;
using u16x8  = __attribute__((ext_vector_type(8))) unsigned short;
using u16x4  = __attribute__((ext_vector_type(4))) unsigned short;

__device__ inline unsigned short f2b(float f) {
  unsigned u = __builtin_bit_cast(unsigned, f);
  u += 0x7FFFu + ((u >> 16) & 1u);   // RNE; no NaN/inf in data
  return (unsigned short)(u >> 16);
}
__device__ inline float b2f(unsigned short u) {
  return __builtin_bit_cast(float, ((unsigned)u) << 16);
}

// async global->LDS, 16 B per lane; LDS dest = wave-uniform base + lane*16
__device__ inline void gld16(const void* g, void* l) {
  __builtin_amdgcn_global_load_lds(
      (__attribute__((address_space(1))) void*)g,
      (__attribute__((address_space(3))) void*)l, 16, 0, 0);
}

// Tile: [128 rows][32 u16] = 64 B/row, chunk (16B) swizzle: slot = chunk ^ ((row>>1)&3).
// ds_read_b128 fragment reads are then perfectly bank-balanced (max 2-way = free).
__device__ inline bf16x8 ld_frag_sw(const unsigned short* lds, int row, int quad) {
  const int sl = quad ^ ((row >> 1) & 3);
  u16x8 v = *(const u16x8*)(lds + row * 32 + sl * 8);
  return __builtin_bit_cast(bf16x8, v);
}

#define MFMA(a, b, c) __builtin_amdgcn_mfma_f32_16x16x32_bf16((a), (b), (c), 0, 0, 0)

// ---------------- K0: split X,W into hi/lo bf16; build x2T bf16 -----------------
__global__ __launch_bounds__(256) void k_split(
    const float* __restrict__ x1, const float* __restrict__ x2,
    const float* __restrict__ W,
    unsigned short* __restrict__ Xh, unsigned short* __restrict__ Xl,
    unsigned short* __restrict__ Wh, unsigned short* __restrict__ Wl,
    unsigned short* __restrict__ x2T)
{
  __shared__ unsigned short tile[64][72];
  const int tid = threadIdx.x;
  const int bx  = blockIdx.x;

  if (bx < XB_) {
    const size_t idx = (size_t)bx * 256 + tid;          // f32x4 index over [32768][768]
    const int row = (int)(idx / 192);
    const int col = ((int)(idx % 192)) * 4;
    const float* src = (row < M1_) ? (x1 + (size_t)row * H_ + col)
                                   : (x2 + (size_t)(row - M1_) * H_ + col);
    f32x4 v = *(const f32x4*)src;
    u16x4 h, l;
#pragma unroll
    for (int q = 0; q < 4; ++q) { h[q] = f2b(v[q]); l[q] = f2b(v[q] - b2f(h[q])); }
    *(u16x4*)(Xh + idx * 4) = h;
    *(u16x4*)(Xl + idx * 4) = l;
  } else if (bx < XB_ + WB_) {
    const int idx = (bx - XB_) * 256 + tid;
    f32x4 v = *(const f32x4*)(W + (size_t)idx * 4);
    u16x4 h, l;
#pragma unroll
    for (int q = 0; q < 4; ++q) { h[q] = f2b(v[q]); l[q] = f2b(v[q] - b2f(h[q])); }
    *(u16x4*)(Wh + (size_t)idx * 4) = h;
    *(u16x4*)(Wl + (size_t)idx * 4) = l;
  } else {
    const int t  = bx - (XB_ + WB_);
    const int b  = t / 192;
    const int r  = t % 192;
    const int j0 = (r / 12) * 64;
    const int d0 = (r % 12) * 64;
#pragma unroll
    for (int p = 0; p < 4; ++p) {
      const int idx = tid + p * 256;
      const int jr  = idx >> 4;
      const int dc  = (idx & 15) * 4;
      f32x4 v = *(const f32x4*)(x2 + ((size_t)(b * L_ + j0 + jr)) * H_ + d0 + dc);
#pragma unroll
      for (int q = 0; q < 4; ++q) tile[jr][dc + q] = f2b(v[q]);
    }
    __syncthreads();
#pragma unroll
    for (int p = 0; p < 2; ++p) {
      const int idx = tid + p * 256;
      const int dr  = idx >> 3;
      const int jc  = (idx & 7) * 8;
      u16x8 o;
#pragma unroll
      for (int q = 0; q < 8; ++q) o[q] = tile[jc + q][dr];
      *(u16x8*)(x2T + ((size_t)(b * H_) + d0 + dr) * L_ + j0 + jc) = o;
    }
  }
}

// ---------------- K1: P = relu(X @ W^T + b), 3-pass hi/lo, store Ph/Pl ----------
__global__ __launch_bounds__(256) void k_proj(
    const unsigned short* __restrict__ Xh, const unsigned short* __restrict__ Xl,
    const unsigned short* __restrict__ Wh, const unsigned short* __restrict__ Wl,
    const float* __restrict__ bias,
    unsigned short* __restrict__ Ph, unsigned short* __restrict__ Pl)
{
  __shared__ unsigned short Ah[128 * 32];
  __shared__ unsigned short Al[128 * 32];
  __shared__ unsigned short Bh[128 * 32];
  __shared__ unsigned short Bl[128 * 32];

  const int tid  = threadIdx.x;
  const int lane = tid & 63, wv = tid >> 6;
  const int wr = wv >> 1, wc = wv & 1;
  const int quad = lane >> 4, lx = lane & 15;
  const int lr = lane >> 2, ls = lane & 3;
  const int lsw = ls ^ ((lr >> 1) & 3);       // fetch this chunk into slot ls

  const int n0 = blockIdx.x * 128;
  const int m0 = blockIdx.y * 128;

  f32x4 acc[4][4] = {};

  for (int k0 = 0; k0 < H_; k0 += 32) {
    __syncthreads();
#pragma unroll
    for (int g = 0; g < 2; ++g) {
      const int rowl = wv * 32 + g * 16;
      const int row  = rowl + lr;
      const size_t ga = (size_t)(m0 + row) * H_ + k0 + lsw * 8;
      const size_t gb = (size_t)(n0 + row) * H_ + k0 + lsw * 8;
      gld16(Xh + ga, &Ah[rowl * 32]);
      gld16(Xl + ga, &Al[rowl * 32]);
      gld16(Wh + gb, &Bh[rowl * 32]);
      gld16(Wl + gb, &Bl[rowl * 32]);
    }
    __syncthreads();

    bf16x8 fah[4], fal[4], fbh[4], fbl[4];
#pragma unroll
    for (int t = 0; t < 4; ++t) {
      fah[t] = ld_frag_sw(Ah, wr * 64 + t * 16 + lx, quad);
      fal[t] = ld_frag_sw(Al, wr * 64 + t * 16 + lx, quad);
      fbh[t] = ld_frag_sw(Bh, wc * 64 + t * 16 + lx, quad);
      fbl[t] = ld_frag_sw(Bl, wc * 64 + t * 16 + lx, quad);
    }
#pragma unroll
    for (int i = 0; i < 4; ++i)
#pragma unroll
      for (int j = 0; j < 4; ++j) acc[i][j] = MFMA(fah[i], fbh[j], acc[i][j]);
#pragma unroll
    for (int i = 0; i < 4; ++i)
#pragma unroll
      for (int j = 0; j < 4; ++j) acc[i][j] = MFMA(fah[i], fbl[j], acc[i][j]);
#pragma unroll
    for (int i = 0; i < 4; ++i)
#pragma unroll
      for (int j = 0; j < 4; ++j) acc[i][j] = MFMA(fal[i], fbh[j], acc[i][j]);
  }

#pragma unroll
  for (int j = 0; j < 4; ++j) {
    const int h = n0 + wc * 64 + j * 16 + lx;
    const float bv = bias[h];
#pragma unroll
    for (int i = 0; i < 4; ++i) {
      const int mb = m0 + wr * 64 + i * 16 + quad * 4;
#pragma unroll
      for (int r = 0; r < 4; ++r) {
        float v = acc[i][j][r] + bv;
        v = v > 0.f ? v : 0.f;
        const unsigned short hh = f2b(v);
        const unsigned short ll = f2b(v - b2f(hh));
        const size_t off = (size_t)(mb + r) * H_ + h;
        Ph[off] = hh;
        Pl[off] = ll;
      }
    }
  }
}

// ---------------- K2: scores = P1·P2^T (3-pass), masked -------------------------
__global__ __launch_bounds__(256) void k_scores(
    const unsigned short* __restrict__ Ph, const unsigned short* __restrict__ Pl,
    const int* __restrict__ x2_mask, float* __restrict__ scores)
{
  __shared__ unsigned short Ah[128 * 32];
  __shared__ unsigned short Al[128 * 32];
  __shared__ unsigned short Bh[128 * 32];
  __shared__ unsigned short Bl[128 * 32];

  const int tid  = threadIdx.x;
  const int lane = tid & 63, wv = tid >> 6;
  const int wr = wv >> 1, wc = wv & 1;
  const int quad = lane >> 4, lx = lane & 15;
  const int lr = lane >> 2, ls = lane & 3;
  const int lsw = ls ^ ((lr >> 1) & 3);

  const int j0 = blockIdx.x * 128;
  const int i0 = blockIdx.y * 128;
  const int b  = blockIdx.z;

  f32x4 acc[4][4] = {};

  for (int k0 = 0; k0 < H_; k0 += 32) {
    __syncthreads();
#pragma unroll
    for (int g = 0; g < 2; ++g) {
      const int rowl = wv * 32 + g * 16;
      const int row  = rowl + lr;
      const size_t ga = (size_t)(b * L_ + i0 + row) * H_ + k0 + lsw * 8;
      const size_t gb = (size_t)(M1_ + b * L_ + j0 + row) * H_ + k0 + lsw * 8;
      gld16(Ph + ga, &Ah[rowl * 32]);
      gld16(Pl + ga, &Al[rowl * 32]);
      gld16(Ph + gb, &Bh[rowl * 32]);
      gld16(Pl + gb, &Bl[rowl * 32]);
    }
    __syncthreads();

    bf16x8 fah[4], fal[4], fbh[4], fbl[4];
#pragma unroll
    for (int t = 0; t < 4; ++t) {
      fah[t] = ld_frag_sw(Ah, wr * 64 + t * 16 + lx, quad);
      fal[t] = ld_frag_sw(Al, wr * 64 + t * 16 + lx, quad);
      fbh[t] = ld_frag_sw(Bh, wc * 64 + t * 16 + lx, quad);
      fbl[t] = ld_frag_sw(Bl, wc * 64 + t * 16 + lx, quad);
    }
#pragma unroll
    for (int i = 0; i < 4; ++i)
#pragma unroll
      for (int j = 0; j < 4; ++j) acc[i][j] = MFMA(fah[i], fbh[j], acc[i][j]);
#pragma unroll
    for (int i = 0; i < 4; ++i)
#pragma unroll
      for (int j = 0; j < 4; ++j) acc[i][j] = MFMA(fah[i], fbl[j], acc[i][j]);
#pragma unroll
    for (int i = 0; i < 4; ++i)
#pragma unroll
      for (int j = 0; j < 4; ++j) acc[i][j] = MFMA(fal[i], fbh[j], acc[i][j]);
  }

#pragma unroll
  for (int j = 0; j < 4; ++j) {
    const int jj = j0 + wc * 64 + j * 16 + lx;
    const int mv = x2_mask[b * L_ + jj];
#pragma unroll
    for (int i = 0; i < 4; ++i) {
      const int ib = i0 + wr * 64 + i * 16 + quad * 4;
#pragma unroll
      for (int r = 0; r < 4; ++r) {
        const float v = mv ? -1e30f : acc[i][j][r];
        scores[((size_t)(b * L_) + ib + r) * L_ + jj] = v;
      }
    }
  }
}

// ---------------- K3: row softmax, fp32 in -> bf16 alpha out --------------------
__global__ __launch_bounds__(256) void k_softmax(
    const float* __restrict__ scores, unsigned short* __restrict__ alphab)
{
  const size_t row = blockIdx.x;
  const float* p = scores + row * L_;
  const int tid = threadIdx.x;

  f32x4 v = *(const f32x4*)(p + tid * 4);
  float m = fmaxf(fmaxf(v[0], v[1]), fmaxf(v[2], v[3]));
#pragma unroll
  for (int off = 32; off > 0; off >>= 1) m = fmaxf(m, __shfl_down(m, off));

  __shared__ float rmax[4];
  __shared__ float rsum[4];
  const int wid = tid >> 6, lane = tid & 63;
  if (lane == 0) rmax[wid] = m;
  __syncthreads();
  m = fmaxf(fmaxf(rmax[0], rmax[1]), fmaxf(rmax[2], rmax[3]));

  f32x4 e;
#pragma unroll
  for (int q = 0; q < 4; ++q) e[q] = __expf(v[q] - m);
  float s = e[0] + e[1] + e[2] + e[3];
#pragma unroll
  for (int off = 32; off > 0; off >>= 1) s += __shfl_down(s, off);
  if (lane == 0) rsum[wid] = s;
  __syncthreads();
  s = rsum[0] + rsum[1] + rsum[2] + rsum[3];

  const float inv = 1.0f / s;
  u16x4 o;
#pragma unroll
  for (int q = 0; q < 4; ++q) o[q] = f2b(e[q] * inv);
  *(u16x4*)(alphab + row * L_ + tid * 4) = o;
}

// ---------------- K4: att = alpha @ x2 (bf16 single-pass) -----------------------
__global__ __launch_bounds__(256) void k_att(
    const unsigned short* __restrict__ alphab, const unsigned short* __restrict__ x2T,
    float* __restrict__ att)
{
  __shared__ unsigned short Aa[128 * 32];
  __shared__ unsigned short Bt[128 * 32];

  const int tid  = threadIdx.x;
  const int lane = tid & 63, wv = tid >> 6;
  const int wr = wv >> 1, wc = wv & 1;
  const int quad = lane >> 4, lx = lane & 15;
  const int lr = lane >> 2, ls = lane & 3;
  const int lsw = ls ^ ((lr >> 1) & 3);

  const int d0 = blockIdx.x * 128;
  const int i0 = blockIdx.y * 128;
  const int b  = blockIdx.z;

  f32x4 acc[4][4] = {};

  for (int j0 = 0; j0 < L_; j0 += 32) {
    __syncthreads();
#pragma unroll
    for (int g = 0; g < 2; ++g) {
      const int rowl = wv * 32 + g * 16;
      const int row  = rowl + lr;
      const size_t ga = (size_t)(b * L_ + i0 + row) * L_ + j0 + lsw * 8;
      const size_t gb = ((size_t)(b * H_) + d0 + row) * L_ + j0 + lsw * 8;
      gld16(alphab + ga, &Aa[rowl * 32]);
      gld16(x2T + gb, &Bt[rowl * 32]);
    }
    __syncthreads();

    bf16x8 fa[4], fb[4];
#pragma unroll
    for (int t = 0; t < 4; ++t) {
      fa[t] = ld_frag_sw(Aa, wr * 64 + t * 16 + lx, quad);
      fb[t] = ld_frag_sw(Bt, wc * 64 + t * 16 + lx, quad);
    }
#pragma unroll
    for (int i = 0; i < 4; ++i)
#pragma unroll
      for (int j = 0; j < 4; ++j)
        acc[i][j] = MFMA(fa[i], fb[j], acc[i][j]);
  }

#pragma unroll
  for (int j = 0; j < 4; ++j) {
    const int dd = d0 + wc * 64 + j * 16 + lx;
#pragma unroll
    for (int i = 0; i < 4; ++i) {
      const int ib = i0 + wr * 64 + i * 16 + quad * 4;
#pragma unroll
      for (int r = 0; r < 4; ++r)
        att[((size_t)(b * L_) + ib + r) * H_ + dd] = acc[i][j][r];
    }
  }
}

// ---------------- K5: out = [x1, att, x1*att, x1-att] ---------------------------
__global__ __launch_bounds__(256) void k_concat(
    const float* __restrict__ x1, const float* __restrict__ att,
    float* __restrict__ out)
{
  const int gid = blockIdx.x * 256 + threadIdx.x;
  const int row = gid / 192;
  const int c   = (gid % 192) * 4;

  f32x4 xv = *(const f32x4*)(x1  + (size_t)row * H_ + c);
  f32x4 av = *(const f32x4*)(att + (size_t)row * H_ + c);
  f32x4 mv, sv;
#pragma unroll
  for (int q = 0; q < 4; ++q) { mv[q] = xv[q] * av[q]; sv[q] = xv[q] - av[q]; }

  float* ob = out + (size_t)row * (4 * H_) + c;
  *(f32x4*)(ob)          = xv;
  *(f32x4*)(ob + H_)     = av;
  *(f32x4*)(ob + 2 * H_) = mv;
  *(f32x4*)(ob + 3 * H_) = sv;
}

extern "C" void kernel_launch(void* const* d_in, const int* in_sizes, int n_in,
                              void* d_out, int out_size, void* d_ws, size_t ws_size,
                              hipStream_t stream) {
  const float* x1      = (const float*)d_in[0];
  const float* x2      = (const float*)d_in[1];
  // d_in[2] = x1_mask : unused
  const int*   x2_mask = (const int*)d_in[3];
  const float* W       = (const float*)d_in[4];
  const float* bias    = (const float*)d_in[5];
  float* out = (float*)d_out;

  char* o8 = (char*)d_out;
  unsigned short* Ph     = (unsigned short*)o8;                          // [0, 50331648)
  unsigned short* Pl     = (unsigned short*)(o8 + 50331648);             // [.., 100663296)
  float*          scores = (float*)(o8 + 100663296);                     // [.., 167772160)
  unsigned short* Xh     = (unsigned short*)(o8 + 100663296);            // alias (early)
  unsigned short* Wh     = (unsigned short*)(o8 + 167772160);            // 1.18 MB
  unsigned short* Wl     = (unsigned short*)(o8 + 168951808);            // 1.18 MB
  unsigned short* x2T    = (unsigned short*)(o8 + 170131456);            // 25.2 MB
  unsigned short* alphab = (unsigned short*)o8;                          // alias Ph (late)
  unsigned short* Xl     = (unsigned short*)d_ws;                        // [0, 50331648)
  float*          att    = (float*)d_ws;                                 // alias Xl (late)

  k_split  <<<dim3(XB_ + WB_ + TB_), 256, 0, stream>>>(x1, x2, W, Xh, Xl, Wh, Wl, x2T);
  k_proj   <<<dim3(6, 256),   256, 0, stream>>>(Xh, Xl, Wh, Wl, bias, Ph, Pl);
  k_scores <<<dim3(8, 8, 16), 256, 0, stream>>>(Ph, Pl, x2_mask, scores);
  k_softmax<<<dim3(16384),    256, 0, stream>>>(scores, alphab);
  k_att    <<<dim3(6, 8, 16), 256, 0, stream>>>(scores ? alphab : alphab, x2T, att);
  k_concat <<<dim3(12288),    256, 0, stream>>>(x1, att, out);
}